// Round 1
// baseline (180.079 us; speedup 1.0000x reference)
//
#include <hip/hip_runtime.h>
#include <math.h>

#define B_ 32
#define N_ 2048
#define D_ 512
#define K_ 128
#define GAMMA_ 10.0f
#define EPS_ 1e-12f
#define STEPS_ 10
#define TN_ 32
#define DC_ 16

// ---------------- k1: normalize target_support, store transposed ----------------
__global__ void k_norm_t(const float* __restrict__ ts, float* __restrict__ t_T,
                         float* __restrict__ tt) {
    int k = blockIdx.x;          // 128 blocks
    int lane = threadIdx.x;      // 64 threads
    const float* row = ts + k * D_;
    float x[8];
    float ssq = 0.f;
#pragma unroll
    for (int j = 0; j < 8; ++j) { x[j] = row[lane + 64 * j]; ssq += x[j] * x[j]; }
#pragma unroll
    for (int off = 32; off; off >>= 1) ssq += __shfl_xor(ssq, off);
    float rs = (float)(1.0 / sqrt((double)ssq + 1e-12));
    float tsq = 0.f;
#pragma unroll
    for (int j = 0; j < 8; ++j) {
        float t = x[j] * rs;
        t_T[(lane + 64 * j) * K_ + k] = t;
        tsq += t * t;
    }
#pragma unroll
    for (int off = 32; off; off >>= 1) tsq += __shfl_xor(tsq, off);
    if (lane == 0) tt[k] = tsq;
}

// ---------------- k2: E[b,k,n] = exp(-gamma * cb) ----------------
__global__ __launch_bounds__(256) void k_gemm(const float* __restrict__ features,
                                              const float* __restrict__ t_T,
                                              const float* __restrict__ tt,
                                              float* __restrict__ E) {
    __shared__ float fT[D_][TN_];   // 64 KB, [d][n] transposed
    __shared__ float tl[DC_][K_];   // 8 KB chunk of t_T
    __shared__ float rssh[TN_], ffsh[TN_];

    int tid = threadIdx.x;
    int b = blockIdx.y;
    int n0 = blockIdx.x * TN_;

    // ---- load & transpose f tile, per-row sumsq via 8-lane groups ----
    {
        int n = tid >> 3, dq = tid & 7;
        const float4* frow = (const float4*)(features + ((size_t)(b * N_ + n0 + n)) * D_);
        float ssq = 0.f;
#pragma unroll
        for (int it = 0; it < 16; ++it) {
            int d4 = dq + 8 * it;
            float4 v = frow[d4];
            fT[d4 * 4 + 0][n] = v.x;
            fT[d4 * 4 + 1][n] = v.y;
            fT[d4 * 4 + 2][n] = v.z;
            fT[d4 * 4 + 3][n] = v.w;
            ssq += v.x * v.x + v.y * v.y + v.z * v.z + v.w * v.w;
        }
        ssq += __shfl_xor(ssq, 1);
        ssq += __shfl_xor(ssq, 2);
        ssq += __shfl_xor(ssq, 4);
        if (dq == 0) {
            float rs = (float)(1.0 / sqrt((double)ssq + 1e-12));
            rssh[n] = rs;
            ffsh[n] = ssq * rs * rs;
        }
    }
    __syncthreads();

    int kq = tid >> 3, nq = tid & 7;
    int k0 = kq * 4, nn0 = nq * 4;
    float acc[4][4] = {};

    for (int c = 0; c < D_ / DC_; ++c) {
        // stage t chunk (coalesced float4, linear LDS write)
        const float4* src = (const float4*)(t_T + (size_t)c * DC_ * K_);
        float4* dst = (float4*)&tl[0][0];
        dst[tid] = src[tid];
        dst[tid + 256] = src[tid + 256];
        __syncthreads();
#pragma unroll
        for (int dd = 0; dd < DC_; ++dd) {
            float4 tv = *(const float4*)&tl[dd][k0];
            float4 fv = *(const float4*)&fT[c * DC_ + dd][nn0];
            float tvv[4] = {tv.x, tv.y, tv.z, tv.w};
            float fvv[4] = {fv.x, fv.y, fv.z, fv.w};
#pragma unroll
            for (int i = 0; i < 4; ++i)
#pragma unroll
                for (int j = 0; j < 4; ++j) acc[i][j] += tvv[i] * fvv[j];
        }
        __syncthreads();
    }

    // ---- epilogue: cb -> exp -> E ----
    float ttk[4];
#pragma unroll
    for (int i = 0; i < 4; ++i) ttk[i] = tt[k0 + i];
    float rsj[4], ffj[4];
#pragma unroll
    for (int j = 0; j < 4; ++j) { rsj[j] = rssh[nn0 + j]; ffj[j] = ffsh[nn0 + j]; }
#pragma unroll
    for (int i = 0; i < 4; ++i) {
        float4 o;
        float ov[4];
#pragma unroll
        for (int j = 0; j < 4; ++j) {
            float cb = ttk[i] + ffj[j] - 2.0f * rsj[j] * acc[i][j];
            ov[j] = expf(-GAMMA_ * cb);
        }
        o.x = ov[0]; o.y = ov[1]; o.z = ov[2]; o.w = ov[3];
        *(float4*)&E[((size_t)(b * K_ + k0 + i)) * N_ + n0 + nn0] = o;
    }
}

// ---------------- k3: A0 = exp(-g*c_u), A1 = column sums of E ----------------
__global__ void k_cols(const float* __restrict__ c_u, const float* __restrict__ E,
                       float* __restrict__ A0, float* __restrict__ A1) {
    int g = blockIdx.x * 256 + threadIdx.x;  // B*N threads
    int b = g / N_, n = g % N_;
    const float* col = E + (size_t)b * K_ * N_ + n;
    float s = 0.f;
#pragma unroll 8
    for (int k = 0; k < K_; ++k) s += col[(size_t)k * N_];
    A1[g] = s;
    A0[g] = expf(-GAMMA_ * c_u[g]);
}

// ---------------- k4: collapsed Sinkhorn loop ----------------
__global__ __launch_bounds__(256) void k_sinkhorn(const float* __restrict__ tr,
                                                  const float* __restrict__ A0,
                                                  const float* __restrict__ A1,
                                                  float* __restrict__ out,
                                                  float* __restrict__ wfb) {
    __shared__ float sc0[4], sc1[4], sres[2];
    int b = blockIdx.x, tid = threadIdx.x;
    float mu = tr[b];
    const float nf = (float)N_;
    float a0[8], a1[8], w[8];
#pragma unroll
    for (int r = 0; r < 8; ++r) {
        int n = tid + 256 * r;
        a0[r] = A0[b * N_ + n];
        a1[r] = A1[b * N_ + n];
        w[r] = 1.f;
    }
    float alpha = 1.f, beta = 1.f;
    for (int s = 0; s < STEPS_; ++s) {
        float p0 = 0.f, p1 = 0.f;
#pragma unroll
        for (int r = 0; r < 8; ++r) {
            float cs = w[r] * (alpha * a0[r] + beta * a1[r]);
            w[r] = w[r] / (cs * nf + EPS_);
            p0 += a0[r] * w[r];
            p1 += a1[r] * w[r];
        }
#pragma unroll
        for (int off = 32; off; off >>= 1) {
            p0 += __shfl_xor(p0, off);
            p1 += __shfl_xor(p1, off);
        }
        int wid = tid >> 6;
        if ((tid & 63) == 0) { sc0[wid] = p0; sc1[wid] = p1; }
        __syncthreads();
        if (tid == 0) {
            sres[0] = sc0[0] + sc0[1] + sc0[2] + sc0[3];
            sres[1] = sc1[0] + sc1[1] + sc1[2] + sc1[3];
        }
        __syncthreads();
        float s0 = alpha * sres[0], ss = beta * sres[1];
        alpha *= (1.f - mu) / (s0 + EPS_);
        beta *= mu / (ss + EPS_);
    }
#pragma unroll
    for (int r = 0; r < 8; ++r) {
        int n = tid + 256 * r;
        float cs = w[r] * (alpha * a0[r] + beta * a1[r]);
        float wf = w[r] / (cs * nf + EPS_);
        out[(size_t)b * (K_ + 1) * N_ + n] = alpha * a0[r] * wf;  // row 0 of P
        wfb[b * N_ + n] = beta * wf;
    }
}

// ---------------- k5: P rows 1..K = E * wfb ----------------
__global__ void k_scale(const float* __restrict__ E, const float* __restrict__ wfb,
                        float* __restrict__ out) {
    size_t g = (size_t)blockIdx.x * 256 + threadIdx.x;  // B*K*N/4 threads
    size_t idx = g * 4;
    int b = (int)(idx / (K_ * N_));
    int rem = (int)(idx % (K_ * N_));
    int k = rem / N_, n = rem % N_;
    float4 e = *(const float4*)&E[idx];
    float4 sc = *(const float4*)&wfb[b * N_ + n];
    float4 o;
    o.x = e.x * sc.x; o.y = e.y * sc.y; o.z = e.z * sc.z; o.w = e.w * sc.w;
    *(float4*)&out[((size_t)(b * (K_ + 1) + 1 + k)) * N_ + n] = o;
}

extern "C" void kernel_launch(void* const* d_in, const int* in_sizes, int n_in,
                              void* d_out, int out_size, void* d_ws, size_t ws_size,
                              hipStream_t stream) {
    const float* features = (const float*)d_in[0];
    const float* tr = (const float*)d_in[1];
    const float* c_u = (const float*)d_in[2];
    const float* ts = (const float*)d_in[3];
    float* out = (float*)d_out;

    float* ws = (float*)d_ws;
    float* t_T = ws;                       // D*K
    float* tt = t_T + D_ * K_;             // K
    float* A0 = tt + K_;                   // B*N
    float* A1 = A0 + B_ * N_;              // B*N
    float* wfb = A1 + B_ * N_;             // B*N
    float* E = wfb + B_ * N_;              // B*K*N
    (void)in_sizes; (void)n_in; (void)out_size; (void)ws_size;

    k_norm_t<<<K_, 64, 0, stream>>>(ts, t_T, tt);
    k_gemm<<<dim3(N_ / TN_, B_), 256, 0, stream>>>(features, t_T, tt, E);
    k_cols<<<B_ * N_ / 256, 256, 0, stream>>>(c_u, E, A0, A1);
    k_sinkhorn<<<B_, 256, 0, stream>>>(tr, A0, A1, out, wfb);
    k_scale<<<B_ * K_ * N_ / 1024, 256, 0, stream>>>(E, wfb, out);
}

// Round 3
// 69.383 us; speedup vs baseline: 2.5954x; 2.5954x over previous
//
#include <hip/hip_runtime.h>
#include <math.h>

#define B_ 32
#define N_ 2048
#define D_ 512
#define K_ 128
#define GAMMA_ 10.0f
#define EPS_ 1e-12f
#define STEPS_ 10
#define SHIFT_ 18.0f
#define EXP_NEG_SHIFT_ 1.5229979e-08f  // exp(-18)

typedef _Float16 f16x8 __attribute__((ext_vector_type(8)));
typedef _Float16 f16x4 __attribute__((ext_vector_type(4)));
typedef float f32x16 __attribute__((ext_vector_type(16)));

// ---------------- k1: quantize t to f16 in fragment-swizzled layout ----------------
// tq layout: chunk c (64 d), k, slot s(16B=8 f16): unit = c*1024 + k*8 + (s ^ (k&7))
__global__ void k_prep_t(const float* __restrict__ ts, _Float16* __restrict__ tq,
                         float* __restrict__ rt, float* __restrict__ tnn) {
    int k = blockIdx.x;      // 128
    int lane = threadIdx.x;  // 64
    const float4* rp = (const float4*)(ts + (size_t)k * D_ + lane * 8);
    float4 v0 = rp[0], v1 = rp[1];
    f16x8 hv;
    hv[0] = (_Float16)v0.x; hv[1] = (_Float16)v0.y; hv[2] = (_Float16)v0.z; hv[3] = (_Float16)v0.w;
    hv[4] = (_Float16)v1.x; hv[5] = (_Float16)v1.y; hv[6] = (_Float16)v1.z; hv[7] = (_Float16)v1.w;
    float ssq = 0.f;
#pragma unroll
    for (int j = 0; j < 8; ++j) { float x = (float)hv[j]; ssq += x * x; }
#pragma unroll
    for (int off = 32; off; off >>= 1) ssq += __shfl_xor(ssq, off);
    if (lane == 0) {
        float rtv = (float)(1.0 / sqrt((double)ssq + 1e-12));
        rt[k] = rtv;
        tnn[k] = ssq * rtv * rtv;
    }
    int c = lane >> 3, s = lane & 7;
    int unit = c * 1024 + k * 8 + (s ^ (k & 7));
    *(f16x8*)&tq[(size_t)unit * 8] = hv;
}

// ---------------- k2: MFMA GEMM + exp epilogue + fused column sums ----------------
__global__ __launch_bounds__(256, 2) void k_gemm(
    const float* __restrict__ features,  // [B][N][D] f32
    const _Float16* __restrict__ tq,     // swizzled f16
    const float* __restrict__ rt, const float* __restrict__ tnn,
    _Float16* __restrict__ E,            // [B][K][N] f16, SHIFTED by exp(+18)
    float* __restrict__ A1)              // [B][N], shifted colsums
{
    __shared__ _Float16 Af[2][128 * 64];
    __shared__ _Float16 Bf[2][128 * 64];
    __shared__ float rowssq[128];
    __shared__ float ldsrt[128], ldstnn[128];

    const int tid = threadIdx.x;
    const int b = blockIdx.x >> 4;
    const int n0 = (blockIdx.x & 15) * 128;
    const int w = tid >> 6;
    const int l = tid & 63;
    const int hi = l >> 5;
    const int l31 = l & 31;

    if (tid < 128) { ldsrt[tid] = rt[tid]; ldstnn[tid] = tnn[tid]; }

    const int fq = tid & 3;       // lane within 4-lane row group
    const int r0 = tid >> 2;      // 0..63
    const float4* fbase = (const float4*)(features + ((size_t)(b * N_ + n0)) * D_);
    const float4* abase = (const float4*)tq;

    float ss0 = 0.f, ss1 = 0.f;
    f32x16 acc[4];
#pragma unroll
    for (int m = 0; m < 4; ++m)
#pragma unroll
        for (int i = 0; i < 16; ++i) acc[m][i] = 0.f;

    float4 ar[4];
    float4 br[8];

    auto stage_load = [&](int c) {
#pragma unroll
        for (int r = 0; r < 4; ++r) ar[r] = abase[c * 1024 + r * 256 + tid];
#pragma unroll
        for (int p = 0; p < 2; ++p)
#pragma unroll
            for (int i = 0; i < 4; ++i)
                br[p * 4 + i] = fbase[(size_t)(p * 64 + r0) * 128 + c * 16 + i * 4 + fq];
    };

    auto stage_write = [&](int buf) {
#pragma unroll
        for (int r = 0; r < 4; ++r)
            *(float4*)&Af[buf][(r * 256 + tid) * 8] = ar[r];
#pragma unroll
        for (int p = 0; p < 2; ++p) {
            float ssl = 0.f;
            int ro = p * 64 + r0;
#pragma unroll
            for (int i = 0; i < 4; ++i) {
                float4 v = br[p * 4 + i];
                f16x4 hv;
                hv[0] = (_Float16)v.x; hv[1] = (_Float16)v.y;
                hv[2] = (_Float16)v.z; hv[3] = (_Float16)v.w;
                float q0 = (float)hv[0], q1 = (float)hv[1], q2 = (float)hv[2], q3 = (float)hv[3];
                ssl += q0 * q0 + q1 * q1 + q2 * q2 + q3 * q3;
                int q = i * 4 + fq;          // float4 index within row chunk
                int s = q >> 1;              // 16B slot
                int hh = q & 1;              // half within slot
                int idx = ro * 64 + ((s ^ (ro & 7)) << 3) + hh * 4;  // f16 units
                *(f16x4*)&Bf[buf][idx] = hv;
            }
            if (p == 0) ss0 += ssl; else ss1 += ssl;
        }
    };

    auto compute = [&](int cur) {
#pragma unroll
        for (int ks = 0; ks < 4; ++ks) {
            int sB = ks * 2 + hi;
            int nrow = w * 32 + l31;
            f16x8 bfr = *(const f16x8*)&Bf[cur][nrow * 64 + ((sB ^ (nrow & 7)) << 3)];
#pragma unroll
            for (int m = 0; m < 4; ++m) {
                int k = m * 32 + l31;
                f16x8 afr = *(const f16x8*)&Af[cur][(k * 8 + (sB ^ (k & 7))) * 8];
                acc[m] = __builtin_amdgcn_mfma_f32_32x32x16_f16(afr, bfr, acc[m], 0, 0, 0);
            }
        }
    };

    stage_load(0);
    stage_write(0);
    __syncthreads();

    for (int c = 0; c < 8; ++c) {
        int cur = c & 1;
        if (c < 7) stage_load(c + 1);   // issue global loads early (T14)
        compute(cur);
        if (c < 7) stage_write(cur ^ 1);
        __syncthreads();
    }

    // ---- epilogue ----
    ss0 += __shfl_xor(ss0, 1); ss0 += __shfl_xor(ss0, 2);
    ss1 += __shfl_xor(ss1, 1); ss1 += __shfl_xor(ss1, 2);
    if (fq == 0) { rowssq[r0] = ss0; rowssq[r0 + 64] = ss1; }
    __syncthreads();

    int n = n0 + w * 32 + l31;
    float rsq = rowssq[w * 32 + l31];
    float rf = (float)(1.0 / sqrt((double)rsq + 1e-12));
    float fnn = rsq * rf * rf;
    float cs = 0.f;
#pragma unroll
    for (int m = 0; m < 4; ++m) {
#pragma unroll
        for (int r = 0; r < 16; ++r) {
            int krow = (r & 3) + 8 * (r >> 2) + 4 * hi;
            int k = m * 32 + krow;
            float cb = ldstnn[k] + fnn - 2.0f * ldsrt[k] * rf * acc[m][r];
            float e = expf(SHIFT_ - GAMMA_ * cb);   // shifted into f16 normal range
            _Float16 eh = (_Float16)e;
            cs += (float)eh;                        // sum exactly what we store
            E[((size_t)(b * K_ + k)) * N_ + n] = eh;
        }
    }
    cs += __shfl_xor(cs, 32);
    if (!hi) A1[b * N_ + n] = cs;
}

// ---------------- k4: collapsed Sinkhorn loop (A0 computed inline) ----------------
__global__ __launch_bounds__(256) void k_sinkhorn(const float* __restrict__ tr,
                                                  const float* __restrict__ c_u,
                                                  const float* __restrict__ A1,
                                                  float* __restrict__ out,
                                                  float* __restrict__ wfb) {
    __shared__ float sc0[4], sc1[4], sres[2];
    int b = blockIdx.x, tid = threadIdx.x;
    float mu = tr[b];
    const float nf = (float)N_;
    float a0[8], a1[8], w[8];
#pragma unroll
    for (int r = 0; r < 8; ++r) {
        int n = tid + 256 * r;
        a0[r] = expf(-GAMMA_ * c_u[b * N_ + n]);
        a1[r] = A1[b * N_ + n] * EXP_NEG_SHIFT_;   // undo global shift exactly in f32
        w[r] = 1.f;
    }
    float alpha = 1.f, beta = 1.f;
    for (int s = 0; s < STEPS_; ++s) {
        float p0 = 0.f, p1 = 0.f;
#pragma unroll
        for (int r = 0; r < 8; ++r) {
            float cs = w[r] * (alpha * a0[r] + beta * a1[r]);
            w[r] = w[r] / (cs * nf + EPS_);
            p0 += a0[r] * w[r];
            p1 += a1[r] * w[r];
        }
#pragma unroll
        for (int off = 32; off; off >>= 1) {
            p0 += __shfl_xor(p0, off);
            p1 += __shfl_xor(p1, off);
        }
        int wid = tid >> 6;
        if ((tid & 63) == 0) { sc0[wid] = p0; sc1[wid] = p1; }
        __syncthreads();
        if (tid == 0) {
            sres[0] = sc0[0] + sc0[1] + sc0[2] + sc0[3];
            sres[1] = sc1[0] + sc1[1] + sc1[2] + sc1[3];
        }
        __syncthreads();
        float s0 = alpha * sres[0], ssum = beta * sres[1];
        alpha *= (1.f - mu) / (s0 + EPS_);
        beta *= mu / (ssum + EPS_);
    }
#pragma unroll
    for (int r = 0; r < 8; ++r) {
        int n = tid + 256 * r;
        float cs = w[r] * (alpha * a0[r] + beta * a1[r]);
        float wf = w[r] / (cs * nf + EPS_);
        out[(size_t)b * (K_ + 1) * N_ + n] = alpha * a0[r] * wf;  // row 0
        wfb[b * N_ + n] = beta * wf * EXP_NEG_SHIFT_;             // fold shift for rows 1..K
    }
}

// ---------------- k5: P rows 1..K = E * wfb ----------------
__global__ void k_scale(const _Float16* __restrict__ E, const float* __restrict__ wfb,
                        float* __restrict__ out) {
    size_t g = (size_t)blockIdx.x * 256 + threadIdx.x;
    size_t idx = g * 8;
    int b = (int)(idx >> 18);            // / (K*N) = 2^18
    int rem = (int)(idx & ((K_ * N_) - 1));
    int k = rem >> 11, n = rem & (N_ - 1);
    f16x8 e = *(const f16x8*)&E[idx];
    float4 w0 = *(const float4*)&wfb[b * N_ + n];
    float4 w1 = *(const float4*)&wfb[b * N_ + n + 4];
    float* op = &out[((size_t)(b * (K_ + 1) + 1 + k)) * N_ + n];
    float4 o0, o1;
    o0.x = (float)e[0] * w0.x; o0.y = (float)e[1] * w0.y;
    o0.z = (float)e[2] * w0.z; o0.w = (float)e[3] * w0.w;
    o1.x = (float)e[4] * w1.x; o1.y = (float)e[5] * w1.y;
    o1.z = (float)e[6] * w1.z; o1.w = (float)e[7] * w1.w;
    *(float4*)op = o0;
    *(float4*)(op + 4) = o1;
}

extern "C" void kernel_launch(void* const* d_in, const int* in_sizes, int n_in,
                              void* d_out, int out_size, void* d_ws, size_t ws_size,
                              hipStream_t stream) {
    const float* features = (const float*)d_in[0];
    const float* tr = (const float*)d_in[1];
    const float* c_u = (const float*)d_in[2];
    const float* ts = (const float*)d_in[3];
    float* out = (float*)d_out;

    char* ws = (char*)d_ws;
    _Float16* tq = (_Float16*)ws;                 // 128*512 f16 = 128 KiB
    float* rt = (float*)(ws + 131072);            // 512 B
    float* tnn = (float*)(ws + 131584);           // 512 B
    float* A1 = (float*)(ws + 132096);            // B*N f32 = 256 KiB
    float* wfb = (float*)(ws + 132096 + 262144);  // 256 KiB
    _Float16* E = (_Float16*)(ws + 132096 + 524288);  // B*K*N f16 = 16 MiB
    (void)in_sizes; (void)n_in; (void)out_size; (void)ws_size;

    k_prep_t<<<K_, 64, 0, stream>>>(ts, tq, rt, tnn);
    k_gemm<<<B_ * (N_ / 128), 256, 0, stream>>>(features, tq, rt, tnn, E, A1);
    k_sinkhorn<<<B_, 256, 0, stream>>>(tr, c_u, A1, out, wfb);
    k_scale<<<(B_ * K_ * N_) / (8 * 256), 256, 0, stream>>>(E, wfb, out);
}

// Round 4
// 66.980 us; speedup vs baseline: 2.6886x; 1.0359x over previous
//
#include <hip/hip_runtime.h>
#include <math.h>

#define B_ 32
#define N_ 2048
#define D_ 512
#define K_ 128
#define GAMMA_ 10.0f
#define EPS_ 1e-12f
#define STEPS_ 10
#define SHIFT_ 18.0f
#define EXP_NEG_SHIFT_ 1.5229979e-08f  // exp(-18)

typedef _Float16 f16x8 __attribute__((ext_vector_type(8)));
typedef _Float16 f16x4 __attribute__((ext_vector_type(4)));
typedef float f32x16 __attribute__((ext_vector_type(16)));

// ---------------- k1: quantize t to f16 in MFMA-fragment-contiguous layout ----------------
// unit u (16B = 8 f16) = (c*8 + s)*128 + k   where c = d>>6, s = (d&63)>>3
// => for lane writing k-row: u = lane*128 + k
__global__ void k_prep_t(const float* __restrict__ ts, _Float16* __restrict__ tq,
                         float* __restrict__ rt, float* __restrict__ tnn) {
    int k = blockIdx.x;      // 128
    int lane = threadIdx.x;  // 64
    const float4* rp = (const float4*)(ts + (size_t)k * D_ + lane * 8);
    float4 v0 = rp[0], v1 = rp[1];
    f16x8 hv;
    hv[0] = (_Float16)v0.x; hv[1] = (_Float16)v0.y; hv[2] = (_Float16)v0.z; hv[3] = (_Float16)v0.w;
    hv[4] = (_Float16)v1.x; hv[5] = (_Float16)v1.y; hv[6] = (_Float16)v1.z; hv[7] = (_Float16)v1.w;
    float ssq = 0.f;
#pragma unroll
    for (int j = 0; j < 8; ++j) { float x = (float)hv[j]; ssq += x * x; }
#pragma unroll
    for (int off = 32; off; off >>= 1) ssq += __shfl_xor(ssq, off);
    if (lane == 0) {
        float rtv = (float)(1.0 / sqrt((double)ssq + 1e-12));
        rt[k] = rtv;
        tnn[k] = ssq * rtv * rtv;
    }
    *(f16x8*)&tq[((size_t)lane * 128 + k) * 8] = hv;
}

// ---------------- k2: MFMA GEMM + exp epilogue + fused column sums ----------------
// tile: 128 k  x  64 n, D chunked by 64, grid = B * 32 n-tiles = 1024 blocks
// A (t) fragments read straight from global (L1/L2-resident), no LDS
__global__ __launch_bounds__(256, 4) void k_gemm(
    const float* __restrict__ features,  // [B][N][D] f32
    const _Float16* __restrict__ tq,     // frag-contiguous f16
    const float* __restrict__ rt, const float* __restrict__ tnn,
    _Float16* __restrict__ E,            // [B][K][N] f16, SHIFTED by exp(+18)
    float* __restrict__ A1)              // [B][N], shifted colsums
{
    __shared__ _Float16 Bf[2][64 * 64];  // 16 KB double-buffered f tile
    __shared__ float rowssq[64];
    __shared__ float csum[2][64];
    __shared__ float ldsrt[128], ldstnn[128];

    const int tid = threadIdx.x;
    const int b = blockIdx.x >> 5;
    const int n0 = (blockIdx.x & 31) * 64;
    const int w = tid >> 6;
    const int l = tid & 63;
    const int hi = l >> 5;
    const int l31 = l & 31;
    const int mh = w >> 1;   // k-half (64 rows)
    const int wn = w & 1;    // n-half (32 cols)
    const int nrow = wn * 32 + l31;

    if (tid < 128) { ldsrt[tid] = rt[tid]; ldstnn[tid] = tnn[tid]; }

    const int fq = tid & 3;       // float4 lane within row group
    const int r0 = tid >> 2;      // 0..63 : feature row staged by this thread
    const float4* fbase = (const float4*)(features + ((size_t)(b * N_ + n0)) * D_);

    float ss = 0.f;               // f16-rounded sumsq of feature row r0 (partial)
    f32x16 acc[2];
#pragma unroll
    for (int m = 0; m < 2; ++m)
#pragma unroll
        for (int i = 0; i < 16; ++i) acc[m][i] = 0.f;

    float4 br[4];

    auto stage_load = [&](int c) {
#pragma unroll
        for (int i = 0; i < 4; ++i)
            br[i] = fbase[(size_t)r0 * 128 + c * 16 + i * 4 + fq];
    };

    auto stage_write = [&](int buf) {
#pragma unroll
        for (int i = 0; i < 4; ++i) {
            float4 v = br[i];
            f16x4 hv;
            hv[0] = (_Float16)v.x; hv[1] = (_Float16)v.y;
            hv[2] = (_Float16)v.z; hv[3] = (_Float16)v.w;
            float q0 = (float)hv[0], q1 = (float)hv[1], q2 = (float)hv[2], q3 = (float)hv[3];
            ss += q0 * q0 + q1 * q1 + q2 * q2 + q3 * q3;
            int q = i * 4 + fq;          // float4 index within 64-d chunk
            int s = q >> 1;              // 16B slot 0..7
            int hh = q & 1;              // half within slot
            int idx = r0 * 64 + ((s ^ (r0 & 7)) << 3) + hh * 4;  // f16 units
            *(f16x4*)&Bf[buf][idx] = hv;
        }
    };

    auto compute = [&](int cur, int c) {
#pragma unroll
        for (int ks = 0; ks < 4; ++ks) {
            int sB = ks * 2 + hi;
            f16x8 bfr = *(const f16x8*)&Bf[cur][nrow * 64 + ((sB ^ (nrow & 7)) << 3)];
#pragma unroll
            for (int mf = 0; mf < 2; ++mf) {
                size_t u = (size_t)(c * 8 + sB) * 128 + mh * 64 + mf * 32 + l31;
                f16x8 afr = *(const f16x8*)&tq[u * 8];
                acc[mf] = __builtin_amdgcn_mfma_f32_32x32x16_f16(afr, bfr, acc[mf], 0, 0, 0);
            }
        }
    };

    stage_load(0);
    stage_write(0);
    __syncthreads();

    for (int c = 0; c < 8; ++c) {
        int cur = c & 1;
        if (c < 7) stage_load(c + 1);   // issue next global loads early (T14)
        compute(cur, c);
        if (c < 7) stage_write(cur ^ 1);
        __syncthreads();
    }

    // ---- epilogue ----
    // full row-sumsq: thread staged row r0 entirely -> reduce over fq group
    ss += __shfl_xor(ss, 1);
    ss += __shfl_xor(ss, 2);
    if (fq == 0) rowssq[r0] = ss;
    __syncthreads();

    int n = n0 + nrow;
    float rsq = rowssq[nrow];
    float rf = (float)(1.0 / sqrt((double)rsq + 1e-12));
    float fnn = rsq * rf * rf;
    float cs = 0.f;
#pragma unroll
    for (int mf = 0; mf < 2; ++mf) {
#pragma unroll
        for (int r = 0; r < 16; ++r) {
            int krow = (r & 3) + 8 * (r >> 2) + 4 * hi;
            int k = mh * 64 + mf * 32 + krow;
            float cb = ldstnn[k] + fnn - 2.0f * ldsrt[k] * rf * acc[mf][r];
            float e = expf(SHIFT_ - GAMMA_ * cb);   // shifted into f16 normal range
            _Float16 eh = (_Float16)e;
            cs += (float)eh;                        // sum exactly what we store
            E[((size_t)(b * K_ + k)) * N_ + n] = eh;
        }
    }
    cs += __shfl_xor(cs, 32);                       // merge hi-halves' row sets
    if (!hi) csum[mh][nrow] = cs;
    __syncthreads();
    if (tid < 64) A1[b * N_ + n0 + tid] = csum[0][tid] + csum[1][tid];
}

// ---------------- k4: collapsed Sinkhorn loop (A0 computed inline) ----------------
__global__ __launch_bounds__(256) void k_sinkhorn(const float* __restrict__ tr,
                                                  const float* __restrict__ c_u,
                                                  const float* __restrict__ A1,
                                                  float* __restrict__ out,
                                                  float* __restrict__ wfb) {
    __shared__ float sc0[4], sc1[4], sres[2];
    int b = blockIdx.x, tid = threadIdx.x;
    float mu = tr[b];
    const float nf = (float)N_;
    float a0[8], a1[8], w[8];
#pragma unroll
    for (int r = 0; r < 8; ++r) {
        int n = tid + 256 * r;
        a0[r] = expf(-GAMMA_ * c_u[b * N_ + n]);
        a1[r] = A1[b * N_ + n] * EXP_NEG_SHIFT_;   // undo global shift exactly in f32
        w[r] = 1.f;
    }
    float alpha = 1.f, beta = 1.f;
    for (int s = 0; s < STEPS_; ++s) {
        float p0 = 0.f, p1 = 0.f;
#pragma unroll
        for (int r = 0; r < 8; ++r) {
            float cs = w[r] * (alpha * a0[r] + beta * a1[r]);
            w[r] = w[r] / (cs * nf + EPS_);
            p0 += a0[r] * w[r];
            p1 += a1[r] * w[r];
        }
#pragma unroll
        for (int off = 32; off; off >>= 1) {
            p0 += __shfl_xor(p0, off);
            p1 += __shfl_xor(p1, off);
        }
        int wid = tid >> 6;
        if ((tid & 63) == 0) { sc0[wid] = p0; sc1[wid] = p1; }
        __syncthreads();
        if (tid == 0) {
            sres[0] = sc0[0] + sc0[1] + sc0[2] + sc0[3];
            sres[1] = sc1[0] + sc1[1] + sc1[2] + sc1[3];
        }
        __syncthreads();
        float s0 = alpha * sres[0], ssum = beta * sres[1];
        alpha *= (1.f - mu) / (s0 + EPS_);
        beta *= mu / (ssum + EPS_);
    }
#pragma unroll
    for (int r = 0; r < 8; ++r) {
        int n = tid + 256 * r;
        float cs = w[r] * (alpha * a0[r] + beta * a1[r]);
        float wf = w[r] / (cs * nf + EPS_);
        out[(size_t)b * (K_ + 1) * N_ + n] = alpha * a0[r] * wf;  // row 0
        wfb[b * N_ + n] = beta * wf * EXP_NEG_SHIFT_;             // fold shift for rows 1..K
    }
}

// ---------------- k5: P rows 1..K = E * wfb ----------------
__global__ void k_scale(const _Float16* __restrict__ E, const float* __restrict__ wfb,
                        float* __restrict__ out) {
    size_t g = (size_t)blockIdx.x * 256 + threadIdx.x;
    size_t idx = g * 8;
    int b = (int)(idx >> 18);            // / (K*N) = 2^18
    int rem = (int)(idx & ((K_ * N_) - 1));
    int k = rem >> 11, n = rem & (N_ - 1);
    f16x8 e = *(const f16x8*)&E[idx];
    float4 w0 = *(const float4*)&wfb[b * N_ + n];
    float4 w1 = *(const float4*)&wfb[b * N_ + n + 4];
    float* op = &out[((size_t)(b * (K_ + 1) + 1 + k)) * N_ + n];
    float4 o0, o1;
    o0.x = (float)e[0] * w0.x; o0.y = (float)e[1] * w0.y;
    o0.z = (float)e[2] * w0.z; o0.w = (float)e[3] * w0.w;
    o1.x = (float)e[4] * w1.x; o1.y = (float)e[5] * w1.y;
    o1.z = (float)e[6] * w1.z; o1.w = (float)e[7] * w1.w;
    *(float4*)op = o0;
    *(float4*)(op + 4) = o1;
}

extern "C" void kernel_launch(void* const* d_in, const int* in_sizes, int n_in,
                              void* d_out, int out_size, void* d_ws, size_t ws_size,
                              hipStream_t stream) {
    const float* features = (const float*)d_in[0];
    const float* tr = (const float*)d_in[1];
    const float* c_u = (const float*)d_in[2];
    const float* ts = (const float*)d_in[3];
    float* out = (float*)d_out;

    char* ws = (char*)d_ws;
    _Float16* tq = (_Float16*)ws;                 // 128*512 f16 = 128 KiB
    float* rt = (float*)(ws + 131072);            // 512 B
    float* tnn = (float*)(ws + 131584);           // 512 B
    float* A1 = (float*)(ws + 132096);            // B*N f32 = 256 KiB
    float* wfb = (float*)(ws + 132096 + 262144);  // 256 KiB
    _Float16* E = (_Float16*)(ws + 132096 + 524288);  // B*K*N f16 = 16 MiB
    (void)in_sizes; (void)n_in; (void)out_size; (void)ws_size;

    k_prep_t<<<K_, 64, 0, stream>>>(ts, tq, rt, tnn);
    k_gemm<<<B_ * 32, 256, 0, stream>>>(features, tq, rt, tnn, E, A1);
    k_sinkhorn<<<B_, 256, 0, stream>>>(tr, c_u, A1, out, wfb);
    k_scale<<<(B_ * K_ * N_) / (8 * 256), 256, 0, stream>>>(E, wfb, out);
}

// Round 6
// 58.470 us; speedup vs baseline: 3.0799x; 1.1455x over previous
//
#include <hip/hip_runtime.h>
#include <math.h>

#define B_ 32
#define N_ 2048
#define D_ 512
#define K_ 128
#define GAMMA_ 10.0f
#define EPS_ 1e-12f
#define STEPS_ 10
#define SHIFT_ 18.0f
#define EXP_NEG_SHIFT_ 1.5229979e-08f  // exp(-18)

typedef _Float16 f16x8 __attribute__((ext_vector_type(8)));
typedef _Float16 f16x4 __attribute__((ext_vector_type(4)));
typedef float f32x16 __attribute__((ext_vector_type(16)));

// ---------------- k1: quantize t to f16 in MFMA-fragment-contiguous layout ----------------
// unit u (16B = 8 f16) = (c*8 + s)*128 + k   where c = d>>6, s = (d&63)>>3
__global__ void k_prep_t(const float* __restrict__ ts, _Float16* __restrict__ tq,
                         float* __restrict__ rt, float* __restrict__ tnn) {
    int k = blockIdx.x;      // 128
    int lane = threadIdx.x;  // 64
    const float4* rp = (const float4*)(ts + (size_t)k * D_ + lane * 8);
    float4 v0 = rp[0], v1 = rp[1];
    f16x8 hv;
    hv[0] = (_Float16)v0.x; hv[1] = (_Float16)v0.y; hv[2] = (_Float16)v0.z; hv[3] = (_Float16)v0.w;
    hv[4] = (_Float16)v1.x; hv[5] = (_Float16)v1.y; hv[6] = (_Float16)v1.z; hv[7] = (_Float16)v1.w;
    float ssq = 0.f;
#pragma unroll
    for (int j = 0; j < 8; ++j) { float x = (float)hv[j]; ssq += x * x; }
#pragma unroll
    for (int off = 32; off; off >>= 1) ssq += __shfl_xor(ssq, off);
    if (lane == 0) {
        float rtv = (float)(1.0 / sqrt((double)ssq + 1e-12));
        rt[k] = rtv;
        tnn[k] = ssq * rtv * rtv;
    }
    *(f16x8*)&tq[((size_t)lane * 128 + k) * 8] = hv;
}

// ---------------- k2: MFMA GEMM + exp epilogue + fused column sums ----------------
// tile: 128 k x 32 n, D chunked by 64, grid = B * 64 n-tiles = 2048 blocks
// wave w owns k rows [w*32, w*32+32); A (t) fragments read straight from global (L2-resident)
__global__ __launch_bounds__(256, 6) void k_gemm(
    const float* __restrict__ features,  // [B][N][D] f32
    const _Float16* __restrict__ tq,     // frag-contiguous f16
    const float* __restrict__ rt, const float* __restrict__ tnn,
    _Float16* __restrict__ E,            // [B][K][N] f16, SHIFTED by exp(+18)
    float* __restrict__ A1)              // [B][N], shifted colsums
{
    __shared__ _Float16 Bf[2][32 * 64];  // 8 KB double-buffered f tile
    __shared__ float rowssq[32];
    __shared__ float csum[4][32];
    __shared__ float ldsrt[128], ldstnn[128];

    const int tid = threadIdx.x;
    const int b = blockIdx.x >> 6;
    const int n0 = (blockIdx.x & 63) * 32;
    const int w = tid >> 6;       // wave id: k rows [w*32, w*32+32)
    const int l = tid & 63;
    const int hi = l >> 5;
    const int l31 = l & 31;

    if (tid < 128) { ldsrt[tid] = rt[tid]; ldstnn[tid] = tnn[tid]; }

    const int fq = tid & 7;       // float4 sub-position within row chunk
    const int r0 = tid >> 3;      // 0..31 : feature row staged by this thread
    const float4* fbase = (const float4*)(features + ((size_t)(b * N_ + n0)) * D_);

    float ss = 0.f;               // f16-rounded partial sumsq of feature row r0
    f32x16 acc;
#pragma unroll
    for (int i = 0; i < 16; ++i) acc[i] = 0.f;

    float4 br[2];

    auto stage_load = [&](int c) {
#pragma unroll
        for (int i = 0; i < 2; ++i)
            br[i] = fbase[(size_t)r0 * 128 + c * 16 + fq + i * 8];
    };

    auto stage_write = [&](int buf) {
#pragma unroll
        for (int i = 0; i < 2; ++i) {
            float4 v = br[i];
            f16x4 hv;
            hv[0] = (_Float16)v.x; hv[1] = (_Float16)v.y;
            hv[2] = (_Float16)v.z; hv[3] = (_Float16)v.w;
            float q0 = (float)hv[0], q1 = (float)hv[1], q2 = (float)hv[2], q3 = (float)hv[3];
            ss += q0 * q0 + q1 * q1 + q2 * q2 + q3 * q3;
            int q = fq + i * 8;          // float4 index within 64-d chunk (0..15)
            int s = q >> 1;              // 16B slot 0..7
            int hh = q & 1;              // half within slot
            int idx = r0 * 64 + ((s ^ (r0 & 7)) << 3) + hh * 4;  // f16 units
            *(f16x4*)&Bf[buf][idx] = hv;
        }
    };

    auto compute = [&](int cur, int c) {
#pragma unroll
        for (int ks = 0; ks < 4; ++ks) {
            int sB = ks * 2 + hi;
            f16x8 bfr = *(const f16x8*)&Bf[cur][l31 * 64 + ((sB ^ (l31 & 7)) << 3)];
            size_t u = (size_t)(c * 8 + sB) * 128 + w * 32 + l31;
            f16x8 afr = *(const f16x8*)&tq[u * 8];
            acc = __builtin_amdgcn_mfma_f32_32x32x16_f16(afr, bfr, acc, 0, 0, 0);
        }
    };

    stage_load(0);
    stage_write(0);
    __syncthreads();

    for (int c = 0; c < 8; ++c) {
        int cur = c & 1;
        if (c < 7) stage_load(c + 1);   // issue next global loads early (T14)
        compute(cur, c);
        if (c < 7) stage_write(cur ^ 1);
        __syncthreads();
    }

    // ---- epilogue ----
    // full row-sumsq: row r0 is split across the 8 lanes with same r0 (same wave)
    ss += __shfl_xor(ss, 1);
    ss += __shfl_xor(ss, 2);
    ss += __shfl_xor(ss, 4);
    if (fq == 0) rowssq[r0] = ss;
    __syncthreads();

    const int n = n0 + l31;
    float rsq = rowssq[l31];
    float rf = (float)(1.0 / sqrt((double)rsq + 1e-12));
    float fnn = rsq * rf * rf;
    float cs = 0.f;
#pragma unroll
    for (int r = 0; r < 16; ++r) {
        int krow = (r & 3) + 8 * (r >> 2) + 4 * hi;
        int k = w * 32 + krow;
        float cb = ldstnn[k] + fnn - 2.0f * ldsrt[k] * rf * acc[r];
        float e = expf(SHIFT_ - GAMMA_ * cb);   // shifted into f16 normal range
        _Float16 eh = (_Float16)e;
        cs += (float)eh;                        // sum exactly what we store
        E[((size_t)(b * K_ + k)) * N_ + n] = eh;
    }
    cs += __shfl_xor(cs, 32);                   // merge hi-half's k rows
    if (!hi) csum[w][l31] = cs;
    __syncthreads();
    if (tid < 32)
        A1[b * N_ + n0 + tid] = csum[0][tid] + csum[1][tid] + csum[2][tid] + csum[3][tid];
}

// ---------------- k4: collapsed Sinkhorn loop (A0 computed inline) ----------------
__global__ __launch_bounds__(256) void k_sinkhorn(const float* __restrict__ tr,
                                                  const float* __restrict__ c_u,
                                                  const float* __restrict__ A1,
                                                  float* __restrict__ out,
                                                  float* __restrict__ wfb) {
    __shared__ float sc0[4], sc1[4], sres[2];
    int b = blockIdx.x, tid = threadIdx.x;
    float mu = tr[b];
    const float nf = (float)N_;
    float a0[8], a1[8], w[8];
#pragma unroll
    for (int r = 0; r < 8; ++r) {
        int n = tid + 256 * r;
        a0[r] = expf(-GAMMA_ * c_u[b * N_ + n]);
        a1[r] = A1[b * N_ + n] * EXP_NEG_SHIFT_;   // undo global shift exactly in f32
        w[r] = 1.f;
    }
    float alpha = 1.f, beta = 1.f;
    for (int s = 0; s < STEPS_; ++s) {
        float p0 = 0.f, p1 = 0.f;
#pragma unroll
        for (int r = 0; r < 8; ++r) {
            float cs = w[r] * (alpha * a0[r] + beta * a1[r]);
            w[r] = w[r] / (cs * nf + EPS_);
            p0 += a0[r] * w[r];
            p1 += a1[r] * w[r];
        }
#pragma unroll
        for (int off = 32; off; off >>= 1) {
            p0 += __shfl_xor(p0, off);
            p1 += __shfl_xor(p1, off);
        }
        int wid = tid >> 6;
        if ((tid & 63) == 0) { sc0[wid] = p0; sc1[wid] = p1; }
        __syncthreads();
        if (tid == 0) {
            sres[0] = sc0[0] + sc0[1] + sc0[2] + sc0[3];
            sres[1] = sc1[0] + sc1[1] + sc1[2] + sc1[3];
        }
        __syncthreads();
        float s0 = alpha * sres[0], ssum = beta * sres[1];
        alpha *= (1.f - mu) / (s0 + EPS_);
        beta *= mu / (ssum + EPS_);
    }
#pragma unroll
    for (int r = 0; r < 8; ++r) {
        int n = tid + 256 * r;
        float cs = w[r] * (alpha * a0[r] + beta * a1[r]);
        float wf = w[r] / (cs * nf + EPS_);
        out[(size_t)b * (K_ + 1) * N_ + n] = alpha * a0[r] * wf;  // row 0
        wfb[b * N_ + n] = beta * wf * EXP_NEG_SHIFT_;             // fold shift for rows 1..K
    }
}

// ---------------- k5: P rows 1..K = E * wfb ----------------
__global__ void k_scale(const _Float16* __restrict__ E, const float* __restrict__ wfb,
                        float* __restrict__ out) {
    size_t g = (size_t)blockIdx.x * 256 + threadIdx.x;
    size_t idx = g * 8;
    int b = (int)(idx >> 18);            // / (K*N) = 2^18
    int rem = (int)(idx & ((K_ * N_) - 1));
    int k = rem >> 11, n = rem & (N_ - 1);
    f16x8 e = *(const f16x8*)&E[idx];
    float4 w0 = *(const float4*)&wfb[b * N_ + n];
    float4 w1 = *(const float4*)&wfb[b * N_ + n + 4];
    float* op = &out[((size_t)(b * (K_ + 1) + 1 + k)) * N_ + n];
    float4 o0, o1;
    o0.x = (float)e[0] * w0.x; o0.y = (float)e[1] * w0.y;
    o0.z = (float)e[2] * w0.z; o0.w = (float)e[3] * w0.w;
    o1.x = (float)e[4] * w1.x; o1.y = (float)e[5] * w1.y;
    o1.z = (float)e[6] * w1.z; o1.w = (float)e[7] * w1.w;
    *(float4*)op = o0;
    *(float4*)(op + 4) = o1;
}

extern "C" void kernel_launch(void* const* d_in, const int* in_sizes, int n_in,
                              void* d_out, int out_size, void* d_ws, size_t ws_size,
                              hipStream_t stream) {
    const float* features = (const float*)d_in[0];
    const float* tr = (const float*)d_in[1];
    const float* c_u = (const float*)d_in[2];
    const float* ts = (const float*)d_in[3];
    float* out = (float*)d_out;

    char* ws = (char*)d_ws;
    _Float16* tq = (_Float16*)ws;                 // 128*512 f16 = 128 KiB
    float* rt = (float*)(ws + 131072);            // 512 B
    float* tnn = (float*)(ws + 131584);           // 512 B
    float* A1 = (float*)(ws + 132096);            // B*N f32 = 256 KiB
    float* wfb = (float*)(ws + 132096 + 262144);  // 256 KiB
    _Float16* E = (_Float16*)(ws + 132096 + 524288);  // B*K*N f16 = 16 MiB
    (void)in_sizes; (void)n_in; (void)out_size; (void)ws_size;

    k_prep_t<<<K_, 64, 0, stream>>>(ts, tq, rt, tnn);
    k_gemm<<<B_ * 64, 256, 0, stream>>>(features, tq, rt, tnn, E, A1);
    k_sinkhorn<<<B_, 256, 0, stream>>>(tr, c_u, A1, out, wfb);
    k_scale<<<(B_ * K_ * N_) / (8 * 256), 256, 0, stream>>>(E, wfb, out);
}

// Round 7
// 54.631 us; speedup vs baseline: 3.2963x; 1.0703x over previous
//
#include <hip/hip_runtime.h>
#include <math.h>

#define B_ 32
#define N_ 2048
#define D_ 512
#define K_ 128
#define GAMMA_ 10.0f
#define EPS_ 1e-12f
#define STEPS_ 10
#define SHIFT_ 18.0f
#define EXP_NEG_SHIFT_ 1.5229979e-08f  // exp(-18)

typedef _Float16 f16x8 __attribute__((ext_vector_type(8)));
typedef _Float16 f16x4 __attribute__((ext_vector_type(4)));
typedef float f32x16 __attribute__((ext_vector_type(16)));

// ---------------- k1: quantize t to f16 in MFMA-fragment-contiguous layout ----------------
// unit u (16B = 8 f16) = (c*8 + s)*128 + k   where c = d>>6, s = (d&63)>>3
__global__ void k_prep_t(const float* __restrict__ ts, _Float16* __restrict__ tq,
                         float* __restrict__ rt, float* __restrict__ tnn) {
    int k = blockIdx.x;      // 128
    int lane = threadIdx.x;  // 64
    const float4* rp = (const float4*)(ts + (size_t)k * D_ + lane * 8);
    float4 v0 = rp[0], v1 = rp[1];
    f16x8 hv;
    hv[0] = (_Float16)v0.x; hv[1] = (_Float16)v0.y; hv[2] = (_Float16)v0.z; hv[3] = (_Float16)v0.w;
    hv[4] = (_Float16)v1.x; hv[5] = (_Float16)v1.y; hv[6] = (_Float16)v1.z; hv[7] = (_Float16)v1.w;
    float ssq = 0.f;
#pragma unroll
    for (int j = 0; j < 8; ++j) { float x = (float)hv[j]; ssq += x * x; }
#pragma unroll
    for (int off = 32; off; off >>= 1) ssq += __shfl_xor(ssq, off);
    if (lane == 0) {
        float rtv = (float)(1.0 / sqrt((double)ssq + 1e-12));
        rt[k] = rtv;
        tnn[k] = ssq * rtv * rtv;
    }
    *(f16x8*)&tq[((size_t)lane * 128 + k) * 8] = hv;
}

// ---------------- k2: MFMA GEMM + exp epilogue + fused column sums ----------------
// tile: 128 k x 32 n, D chunked by 64, grid = B * 64 n-tiles = 2048 blocks
// wave w owns k rows [w*32, w*32+32); A (t) fragments register-prefetched from global (L2)
__global__ __launch_bounds__(256, 6) void k_gemm(
    const float* __restrict__ features,  // [B][N][D] f32
    const _Float16* __restrict__ tq,     // frag-contiguous f16
    const float* __restrict__ rt, const float* __restrict__ tnn,
    _Float16* __restrict__ E,            // [B][K][N] f16, SHIFTED by exp(+18)
    float* __restrict__ A1)              // [B][N], shifted colsums
{
    __shared__ _Float16 Bf[2][32 * 64];  // 8 KB double-buffered f tile
    __shared__ float rowssq[32];
    __shared__ float csum[4][32];
    __shared__ float ldsrt[128], ldstnn[128];

    const int tid = threadIdx.x;
    const int b = blockIdx.x >> 6;
    const int n0 = (blockIdx.x & 63) * 32;
    const int w = tid >> 6;       // wave id: k rows [w*32, w*32+32)
    const int l = tid & 63;
    const int hi = l >> 5;
    const int l31 = l & 31;

    if (tid < 128) { ldsrt[tid] = rt[tid]; ldstnn[tid] = tnn[tid]; }

    const int fq = tid & 7;       // float4 sub-position within row chunk
    const int r0 = tid >> 3;      // 0..31 : feature row staged by this thread
    const float4* fbase = (const float4*)(features + ((size_t)(b * N_ + n0)) * D_);

    float ss = 0.f;               // f16-rounded partial sumsq of feature row r0
    f32x16 acc;
#pragma unroll
    for (int i = 0; i < 16; ++i) acc[i] = 0.f;

    float4 br[2];
    f16x8 apre[4];                // register-prefetched A fragments for current chunk

    auto stage_load = [&](int c) {
#pragma unroll
        for (int i = 0; i < 2; ++i)
            br[i] = fbase[(size_t)r0 * 128 + c * 16 + fq + i * 8];
    };

    auto a_load = [&](int c) {
#pragma unroll
        for (int ks = 0; ks < 4; ++ks) {
            int sB = ks * 2 + hi;
            size_t u = (size_t)(c * 8 + sB) * 128 + w * 32 + l31;
            apre[ks] = *(const f16x8*)&tq[u * 8];
        }
    };

    auto stage_write = [&](int buf) {
#pragma unroll
        for (int i = 0; i < 2; ++i) {
            float4 v = br[i];
            f16x4 hv;
            hv[0] = (_Float16)v.x; hv[1] = (_Float16)v.y;
            hv[2] = (_Float16)v.z; hv[3] = (_Float16)v.w;
            float q0 = (float)hv[0], q1 = (float)hv[1], q2 = (float)hv[2], q3 = (float)hv[3];
            ss += q0 * q0 + q1 * q1 + q2 * q2 + q3 * q3;
            int q = fq + i * 8;          // float4 index within 64-d chunk (0..15)
            int s = q >> 1;              // 16B slot 0..7
            int hh = q & 1;              // half within slot
            int idx = r0 * 64 + ((s ^ (r0 & 7)) << 3) + hh * 4;  // f16 units
            *(f16x4*)&Bf[buf][idx] = hv;
        }
    };

    auto compute = [&](int cur) {
#pragma unroll
        for (int ks = 0; ks < 4; ++ks) {
            int sB = ks * 2 + hi;
            f16x8 bfr = *(const f16x8*)&Bf[cur][l31 * 64 + ((sB ^ (l31 & 7)) << 3)];
            acc = __builtin_amdgcn_mfma_f32_32x32x16_f16(apre[ks], bfr, acc, 0, 0, 0);
        }
    };

    stage_load(0);
    a_load(0);
    stage_write(0);
    __syncthreads();

#pragma unroll
    for (int c = 0; c < 8; ++c) {
        int cur = c & 1;
        if (c < 7) stage_load(c + 1);   // issue next feature loads early (T14)
        compute(cur);                    // consumes apre (chunk c) + Bf[cur]
        if (c < 7) a_load(c + 1);        // refill A prefetch (compiler renames -> dbuf)
        if (c < 7) stage_write(cur ^ 1);
        __syncthreads();
    }

    // ---- epilogue ----
    // full row-sumsq: row r0 is split across the 8 lanes with same r0 (same wave)
    ss += __shfl_xor(ss, 1);
    ss += __shfl_xor(ss, 2);
    ss += __shfl_xor(ss, 4);
    if (fq == 0) rowssq[r0] = ss;
    __syncthreads();

    const int n = n0 + l31;
    float rsq = rowssq[l31];
    float rf = (float)(1.0 / sqrt((double)rsq + 1e-12));
    float fnn = rsq * rf * rf;
    float cs = 0.f;
#pragma unroll
    for (int r = 0; r < 16; ++r) {
        int krow = (r & 3) + 8 * (r >> 2) + 4 * hi;
        int k = w * 32 + krow;
        float cb = ldstnn[k] + fnn - 2.0f * ldsrt[k] * rf * acc[r];
        float e = expf(SHIFT_ - GAMMA_ * cb);   // shifted into f16 normal range
        _Float16 eh = (_Float16)e;
        cs += (float)eh;                        // sum exactly what we store
        E[((size_t)(b * K_ + k)) * N_ + n] = eh;
    }
    cs += __shfl_xor(cs, 32);                   // merge hi-half's k rows
    if (!hi) csum[w][l31] = cs;
    __syncthreads();
    if (tid < 32)
        A1[b * N_ + n0 + tid] = csum[0][tid] + csum[1][tid] + csum[2][tid] + csum[3][tid];
}

// ---------------- k4: collapsed Sinkhorn loop (A0 computed inline) ----------------
__global__ __launch_bounds__(256) void k_sinkhorn(const float* __restrict__ tr,
                                                  const float* __restrict__ c_u,
                                                  const float* __restrict__ A1,
                                                  float* __restrict__ out,
                                                  float* __restrict__ wfb) {
    __shared__ float sc0[4], sc1[4], sres[2];
    int b = blockIdx.x, tid = threadIdx.x;
    float mu = tr[b];
    const float nf = (float)N_;
    float a0[8], a1[8], w[8];
#pragma unroll
    for (int r = 0; r < 8; ++r) {
        int n = tid + 256 * r;
        a0[r] = expf(-GAMMA_ * c_u[b * N_ + n]);
        a1[r] = A1[b * N_ + n] * EXP_NEG_SHIFT_;   // undo global shift exactly in f32
        w[r] = 1.f;
    }
    float alpha = 1.f, beta = 1.f;
    for (int s = 0; s < STEPS_; ++s) {
        float p0 = 0.f, p1 = 0.f;
#pragma unroll
        for (int r = 0; r < 8; ++r) {
            float cs = w[r] * (alpha * a0[r] + beta * a1[r]);
            w[r] = w[r] / (cs * nf + EPS_);
            p0 += a0[r] * w[r];
            p1 += a1[r] * w[r];
        }
#pragma unroll
        for (int off = 32; off; off >>= 1) {
            p0 += __shfl_xor(p0, off);
            p1 += __shfl_xor(p1, off);
        }
        int wid = tid >> 6;
        if ((tid & 63) == 0) { sc0[wid] = p0; sc1[wid] = p1; }
        __syncthreads();
        if (tid == 0) {
            sres[0] = sc0[0] + sc0[1] + sc0[2] + sc0[3];
            sres[1] = sc1[0] + sc1[1] + sc1[2] + sc1[3];
        }
        __syncthreads();
        float s0 = alpha * sres[0], ssum = beta * sres[1];
        alpha *= (1.f - mu) / (s0 + EPS_);
        beta *= mu / (ssum + EPS_);
    }
#pragma unroll
    for (int r = 0; r < 8; ++r) {
        int n = tid + 256 * r;
        float cs = w[r] * (alpha * a0[r] + beta * a1[r]);
        float wf = w[r] / (cs * nf + EPS_);
        out[(size_t)b * (K_ + 1) * N_ + n] = alpha * a0[r] * wf;  // row 0
        wfb[b * N_ + n] = beta * wf * EXP_NEG_SHIFT_;             // fold shift for rows 1..K
    }
}

// ---------------- k5: P rows 1..K = E * wfb ----------------
__global__ void k_scale(const _Float16* __restrict__ E, const float* __restrict__ wfb,
                        float* __restrict__ out) {
    size_t g = (size_t)blockIdx.x * 256 + threadIdx.x;
    size_t idx = g * 8;
    int b = (int)(idx >> 18);            // / (K*N) = 2^18
    int rem = (int)(idx & ((K_ * N_) - 1));
    int k = rem >> 11, n = rem & (N_ - 1);
    f16x8 e = *(const f16x8*)&E[idx];
    float4 w0 = *(const float4*)&wfb[b * N_ + n];
    float4 w1 = *(const float4*)&wfb[b * N_ + n + 4];
    float* op = &out[((size_t)(b * (K_ + 1) + 1 + k)) * N_ + n];
    float4 o0, o1;
    o0.x = (float)e[0] * w0.x; o0.y = (float)e[1] * w0.y;
    o0.z = (float)e[2] * w0.z; o0.w = (float)e[3] * w0.w;
    o1.x = (float)e[4] * w1.x; o1.y = (float)e[5] * w1.y;
    o1.z = (float)e[6] * w1.z; o1.w = (float)e[7] * w1.w;
    *(float4*)op = o0;
    *(float4*)(op + 4) = o1;
}

extern "C" void kernel_launch(void* const* d_in, const int* in_sizes, int n_in,
                              void* d_out, int out_size, void* d_ws, size_t ws_size,
                              hipStream_t stream) {
    const float* features = (const float*)d_in[0];
    const float* tr = (const float*)d_in[1];
    const float* c_u = (const float*)d_in[2];
    const float* ts = (const float*)d_in[3];
    float* out = (float*)d_out;

    char* ws = (char*)d_ws;
    _Float16* tq = (_Float16*)ws;                 // 128*512 f16 = 128 KiB
    float* rt = (float*)(ws + 131072);            // 512 B
    float* tnn = (float*)(ws + 131584);           // 512 B
    float* A1 = (float*)(ws + 132096);            // B*N f32 = 256 KiB
    float* wfb = (float*)(ws + 132096 + 262144);  // 256 KiB
    _Float16* E = (_Float16*)(ws + 132096 + 524288);  // B*K*N f16 = 16 MiB
    (void)in_sizes; (void)n_in; (void)out_size; (void)ws_size;

    k_prep_t<<<K_, 64, 0, stream>>>(ts, tq, rt, tnn);
    k_gemm<<<B_ * 64, 256, 0, stream>>>(features, tq, rt, tnn, E, A1);
    k_sinkhorn<<<B_, 256, 0, stream>>>(tr, c_u, A1, out, wfb);
    k_scale<<<(B_ * K_ * N_) / (8 * 256), 256, 0, stream>>>(E, wfb, out);
}